// Round 6
// baseline (21692.099 us; speedup 1.0000x reference)
//
#include <hip/hip_runtime.h>
#include <hip/hip_fp16.h>

typedef _Float16 half8 __attribute__((ext_vector_type(8)));
typedef _Float16 half4_t __attribute__((ext_vector_type(4)));
typedef float    float4_ __attribute__((ext_vector_type(4)));

#define TSTEPS 512
#define NBB 32              // layer-2 blocks (blk 0..31)
#define NAB 32              // layer-1 blocks (blk 32..63)
#define NCB 2               // output blocks  (blk 64..65)
#define NBLK (NBB + NAB + NCB)
#define FSTRIDE 32          // ints per flag slot = 128 B

// workspace layout (bytes)
#define FLB_OFF   0                       // 32 flags x 128B (layer-2)
#define FLA_OFF   4096                    // 32 flags x 128B (layer-1)
#define FLC_OFF   8192                    // 2 flags
#define H1_OFF    16384
#define PH        262144                  // one phase: 1024 cols x 128 b x 2B
#define H2_OFF    (H1_OFF + 2 * PH)       // 540672
#define WA_OFF    (H2_OFF + 2 * PH)       // 1064960
#define WA_SIZE   (32u*2*34*4*64*16)      // 8,912,896
#define WB_OFF    (WA_OFF + WA_SIZE)      // 9,977,856
#define WB_SIZE   (32u*2*64*4*64*16)      // 16,777,216
#define ZERO_BYTES WA_OFF                 // flags + H1 + H2

__device__ __forceinline__ float sigf(float x) { return 1.0f / (1.0f + __expf(-x)); }

__device__ __forceinline__ half8 cvt8(const float* s) {
    float4_ lo = *(const float4_*)s;
    float4_ hi = *(const float4_*)(s + 4);
    half8 r;
    r[0] = (_Float16)lo[0]; r[1] = (_Float16)lo[1];
    r[2] = (_Float16)lo[2]; r[3] = (_Float16)lo[3];
    r[4] = (_Float16)hi[0]; r[5] = (_Float16)hi[1];
    r[6] = (_Float16)hi[2]; r[7] = (_Float16)hi[3];
    return r;
}

// ---- coherence-point primitives (no fences, no cache maintenance) ----
__device__ __forceinline__ half8 ldg_coh16(const void* p) {
    union U { unsigned long long u; half4_t h; };
    U a, b;
    a.u = __hip_atomic_load((const unsigned long long*)p, __ATOMIC_RELAXED,
                            __HIP_MEMORY_SCOPE_AGENT);
    b.u = __hip_atomic_load((const unsigned long long*)p + 1, __ATOMIC_RELAXED,
                            __HIP_MEMORY_SCOPE_AGENT);
    half8 r;
#pragma unroll
    for (int i = 0; i < 4; ++i) { r[i] = a.h[i]; r[i + 4] = b.h[i]; }
    return r;
}

__device__ __forceinline__ void stg_coh_h(void* p, float v) {
    union { _Float16 h; unsigned short s; } u;
    u.h = (_Float16)v;
    unsigned int d = u.s;
    asm volatile("global_store_short %0, %1, off sc0 sc1" :: "v"(p), "v"(d) : "memory");
}

__device__ __forceinline__ void stg_coh_int(void* p, int v) {
    asm volatile("global_store_dword %0, %1, off sc0 sc1" :: "v"(p), "v"(v) : "memory");
}

__device__ __forceinline__ void publish(int* flag, int v) {
    asm volatile("s_waitcnt vmcnt(0)" ::: "memory");
    __syncthreads();
    if (threadIdx.x == 0) stg_coh_int(flag, v);
}

__device__ __forceinline__ int ld_flag(const int* f, int idx) {
    return __hip_atomic_load(f + idx * FSTRIDE, __ATOMIC_RELAXED,
                             __HIP_MEMORY_SCOPE_AGENT);
}

// ---- one-time weight repack: fp32 -> fp16 in exact streaming order ----
// WA frag id = (((a*2+nj)*34+kt)*4+g)*64+lane ; WB analogous with 64 kt
extern "C" __global__ void prep_w(const float* __restrict__ Wih1, const float* __restrict__ Whh1,
                                  const float* __restrict__ Wih2, const float* __restrict__ Whh2,
                                  char* __restrict__ ws) {
    const int id = blockIdx.x * 256 + threadIdx.x;
    const int WAF = 32 * 2 * 34 * 4 * 64;     // 557056
    const float* src;
    char* dst;
    if (id < WAF) {
        int lane = id & 63, g = (id >> 6) & 3, rest = id >> 8;
        int kt = rest % 34, aj = rest / 34, nj = aj & 1, a = aj >> 1;
        int row = g * 1024 + a * 32 + nj * 16 + (lane & 15);
        int k0 = kt * 32 + (lane >> 4) * 8;
        src = (k0 < 64) ? (Wih1 + (size_t)row * 64 + k0)
                        : (Whh1 + (size_t)row * 1024 + (k0 - 64));
        dst = ws + WA_OFF + (size_t)id * 16;
    } else {
        int idb = id - WAF;                    // < 1048576 by grid construction
        int lane = idb & 63, g = (idb >> 6) & 3, kt = (idb >> 8) & 63;
        int nj = (idb >> 14) & 1, b = idb >> 15;
        int row = g * 1024 + b * 32 + nj * 16 + (lane & 15);
        int k0 = kt * 32 + (lane >> 4) * 8;
        src = (k0 < 1024) ? (Wih2 + (size_t)row * 1024 + k0)
                          : (Whh2 + (size_t)row * 1024 + (k0 - 1024));
        dst = ws + WB_OFF + (size_t)idb * 16;
    }
    *(half8*)dst = cvt8(src);
}

__device__ __forceinline__ int wktB(int bb, int kidx) {
    int ch = kidx >> 2, kl = kidx & 3;
    return (ch < 8) ? (32 + ((ch + bb) & 7) * 4 + kl)
                    : (((ch - 8 + bb) & 7) * 4 + kl);
}
__device__ __forceinline__ int wktA(int a, int kidx) {
    if (kidx < 2) return kidx;
    int h = kidx - 2;
    return 2 + (((h >> 2) + a) & 7) * 4 + (h & 3);
}

extern "C" __global__ __launch_bounds__(256, 1)
void lstm_persistent(const float* __restrict__ xin,
                     const float* __restrict__ bih1, const float* __restrict__ bhh1,
                     const float* __restrict__ bih2, const float* __restrict__ bhh2,
                     const float* __restrict__ Wout, const float* __restrict__ bout,
                     char* __restrict__ ws, float* __restrict__ out) {
    const int tid = threadIdx.x;
    const int w = tid >> 6, lane = tid & 63;
    const int quad = lane >> 4, cl = lane & 15;
    const int mi = w & 1, nj = w >> 1;
    const int laneoff = quad * 2048 + cl * 16;
    int* fB = (int*)(ws + FLB_OFF);
    int* fA = (int*)(ws + FLA_OFF);
    int* fC = (int*)(ws + FLC_OFF);
    char* H1 = ws + H1_OFF;
    char* H2 = ws + H2_OFF;
    const int blk = blockIdx.x;
    __shared__ char smem[65536];
    char* const buf0 = smem;
    char* const buf1 = smem + 32768;

    if (blk < NBB) {
        // ================= layer-2: 32 h2 cols, K=2048 (64 kt, 16 chunks of 4) =========
        const int bb = blk;
        const char* WBb = ws + WB_OFF + (size_t)(bb * 2 + nj) * 262144;
        const int colc = bb * 32 + nj * 16 + cl;
        float bias[4];
#pragma unroll
        for (int g = 0; g < 4; ++g) bias[g] = bih2[g * 1024 + colc] + bhh2[g * 1024 + colc];
        float cst[4][4];
#pragma unroll
        for (int i = 0; i < 4; ++i)
#pragma unroll
            for (int r = 0; r < 4; ++r) cst[i][r] = 0.0f;
        const int stoff = (nj * 2 + (cl >> 3)) * 2048 + (cl & 7) * 2;

        for (int t = 0; t < TSTEPS; ++t) {
            // phase 1: h2[t-1] ready (fB>=t) and C done with phase (fC>=t-1)
            if (tid < 64) {
                for (;;) {
                    int b0 = ld_flag(fB, lane & 31);
                    int c0 = ld_flag(fC, lane & 1);
                    if (__all((b0 >= t) && (c0 >= t - 1))) break;
                    __builtin_amdgcn_s_sleep(1);
                }
            }
            __syncthreads();
            const char* h1c = H1 + (size_t)(t & 1) * PH;
            const char* h2r = H2 + (size_t)((t & 1) ^ 1) * PH;
            char*       h2w = H2 + (size_t)(t & 1) * PH;
            // chunk order: h2 first (ready now), h1 after poll2; rotated by bb
            const char* csrc[16];
#pragma unroll
            for (int ch = 0; ch < 16; ++ch)
                csrc[ch] = (ch < 8) ? (h2r + (size_t)((ch + bb) & 7) * 32768)
                                    : (h1c + (size_t)((ch - 8 + bb) & 7) * 32768);
            half8 vs[3][8];
#pragma unroll
            for (int s = 0; s < 3; ++s)
#pragma unroll
                for (int i = 0; i < 8; ++i)
                    vs[s][i] = ldg_coh16(csrc[s] + i * 4096 + tid * 16);
            // phase 2: h1[t] ready
            if (tid < 64) {
                while (!__all(ld_flag(fA, lane & 31) >= t + 1))
                    __builtin_amdgcn_s_sleep(1);
            }
            __syncthreads();
            float4_ acc[4][4];
#pragma unroll
            for (int i = 0; i < 4; ++i)
#pragma unroll
                for (int g = 0; g < 4; ++g) acc[i][g] = (float4_){0.f, 0.f, 0.f, 0.f};
            half8 wfr[2][4];
#pragma unroll
            for (int g = 0; g < 4; ++g) {
                wfr[0][g] = *(const half8*)(WBb + (size_t)wktB(bb, 0) * 4096 + g * 1024 + lane * 16);
                wfr[1][g] = *(const half8*)(WBb + (size_t)wktB(bb, 1) * 4096 + g * 1024 + lane * 16);
            }
#pragma unroll
            for (int i = 0; i < 8; ++i)
                *(half8*)(buf0 + i * 4096 + tid * 16) = vs[0][i];
            __syncthreads();
            half8 af[2][4];
#pragma unroll
            for (int ch = 0; ch < 16; ++ch) {
                if (ch + 3 < 16) {
#pragma unroll
                    for (int i = 0; i < 8; ++i)
                        vs[ch % 3][i] = ldg_coh16(csrc[ch + 3] + i * 4096 + tid * 16);
                }
                const char* bc = (ch & 1) ? buf1 : buf0;
#pragma unroll
                for (int i = 0; i < 4; ++i)
                    af[0][i] = *(const half8*)(bc + laneoff + (mi * 4 + i) * 256);
#pragma unroll
                for (int kl = 0; kl < 4; ++kl) {
                    const int kidx = ch * 4 + kl;
                    if (kl < 3) {
#pragma unroll
                        for (int i = 0; i < 4; ++i)
                            af[(kl + 1) & 1][i] = *(const half8*)(bc + (kl + 1) * 8192 + laneoff + (mi * 4 + i) * 256);
                    }
#pragma unroll
                    for (int i = 0; i < 4; ++i)
#pragma unroll
                        for (int g = 0; g < 4; ++g)
                            acc[i][g] = __builtin_amdgcn_mfma_f32_16x16x32_f16(
                                af[kl & 1][i], wfr[kidx & 1][g], acc[i][g], 0, 0, 0);
                    if (kidx + 2 < 64) {
#pragma unroll
                        for (int g = 0; g < 4; ++g)
                            wfr[kidx & 1][g] = *(const half8*)(WBb + (size_t)wktB(bb, kidx + 2) * 4096 + g * 1024 + lane * 16);
                    }
                }
                if (ch + 1 < 16) {
                    char* bw = ((ch + 1) & 1) ? buf1 : buf0;
#pragma unroll
                    for (int i = 0; i < 8; ++i)
                        *(half8*)(bw + i * 4096 + tid * 16) = vs[(ch + 1) % 3][i];
                }
                __syncthreads();
            }
            // epilogue
#pragma unroll
            for (int i = 0; i < 4; ++i)
#pragma unroll
                for (int r = 0; r < 4; ++r) {
                    float iv = acc[i][0][r] + bias[0];
                    float fv = acc[i][1][r] + bias[1];
                    float gv = acc[i][2][r] + bias[2];
                    float ov = acc[i][3][r] + bias[3];
                    float cn = sigf(fv) * cst[i][r] + sigf(iv) * tanhf(gv);
                    float h  = sigf(ov) * tanhf(cn);
                    cst[i][r] = cn;
                    int brow = (mi * 4 + i) * 16 + quad * 4 + r;
                    stg_coh_h(h2w + bb * 8192 + stoff + brow * 16, h);
                }
            publish(fB + bb * FSTRIDE, t + 1);
        }
    } else if (blk < NBB + NAB) {
        // ================= layer-1: 32 h1 cols, K=1088 (2 kt X + 32 kt h1) =============
        const int a = blk - NBB;
        const char* WAb = ws + WA_OFF + (size_t)(a * 2 + nj) * 139264;
        const int colc = a * 32 + nj * 16 + cl;
        float bias[4];
#pragma unroll
        for (int g = 0; g < 4; ++g) bias[g] = bih1[g * 1024 + colc] + bhh1[g * 1024 + colc];
        float cst[4][4];
#pragma unroll
        for (int i = 0; i < 4; ++i)
#pragma unroll
            for (int r = 0; r < 4; ++r) cst[i][r] = 0.0f;
        const int stoff = (nj * 2 + (cl >> 3)) * 2048 + (cl & 7) * 2;

        for (int t = 0; t < TSTEPS; ++t) {
            // h1[t-1] ready (fA>=t) and B done with this phase (fB>=t-1)
            if (tid < 64) {
                for (;;) {
                    int av = (lane < 32) ? ld_flag(fA, lane) : ld_flag(fB, lane - 32);
                    int thr = (lane < 32) ? t : (t - 1);
                    if (__all(av >= thr)) break;
                    __builtin_amdgcn_s_sleep(1);
                }
            }
            __syncthreads();
            const char* h1r = H1 + (size_t)((t & 1) ^ 1) * PH;
            char*       h1w = H1 + (size_t)(t & 1) * PH;
            const char* csrc[8];
#pragma unroll
            for (int hc = 0; hc < 8; ++hc)
                csrc[hc] = h1r + (size_t)((hc + a) & 7) * 32768;
            half8 vs[3][8];
#pragma unroll
            for (int s = 0; s < 3; ++s)
#pragma unroll
                for (int i = 0; i < 8; ++i)
                    vs[s][i] = ldg_coh16(csrc[s] + i * 4096 + tid * 16);
            // stage X (chunk0, 2 kt) from input via cached loads
            {
                const int q = tid >> 6, bp = tid & 63;
#pragma unroll
                for (int u = 0; u < 4; ++u) {
                    int kt2 = u >> 1, bidx = bp * 2 + (u & 1);
                    const float* xs = xin + (size_t)bidx * 32768 + t * 64 + kt2 * 32 + q * 8;
                    *(half8*)(buf0 + kt2 * 8192 + q * 2048 + bidx * 16) = cvt8(xs);
                }
            }
            float4_ acc[4][4];
#pragma unroll
            for (int i = 0; i < 4; ++i)
#pragma unroll
                for (int g = 0; g < 4; ++g) acc[i][g] = (float4_){0.f, 0.f, 0.f, 0.f};
            half8 wfr[2][4];
#pragma unroll
            for (int g = 0; g < 4; ++g) {
                wfr[0][g] = *(const half8*)(WAb + (size_t)wktA(a, 0) * 4096 + g * 1024 + lane * 16);
                wfr[1][g] = *(const half8*)(WAb + (size_t)wktA(a, 1) * 4096 + g * 1024 + lane * 16);
            }
            __syncthreads();
            half8 af[2][4];
            // chunk 0 (X, 2 kl)
            {
#pragma unroll
                for (int i = 0; i < 4; ++i)
                    af[0][i] = *(const half8*)(buf0 + laneoff + (mi * 4 + i) * 256);
#pragma unroll
                for (int kl = 0; kl < 2; ++kl) {
                    if (kl < 1) {
#pragma unroll
                        for (int i = 0; i < 4; ++i)
                            af[1][i] = *(const half8*)(buf0 + 8192 + laneoff + (mi * 4 + i) * 256);
                    }
#pragma unroll
                    for (int i = 0; i < 4; ++i)
#pragma unroll
                        for (int g = 0; g < 4; ++g)
                            acc[i][g] = __builtin_amdgcn_mfma_f32_16x16x32_f16(
                                af[kl & 1][i], wfr[kl & 1][g], acc[i][g], 0, 0, 0);
#pragma unroll
                    for (int g = 0; g < 4; ++g)
                        wfr[kl & 1][g] = *(const half8*)(WAb + (size_t)wktA(a, kl + 2) * 4096 + g * 1024 + lane * 16);
                }
            }
#pragma unroll
            for (int i = 0; i < 8; ++i)
                *(half8*)(buf1 + i * 4096 + tid * 16) = vs[0][i];
            __syncthreads();
#pragma unroll
            for (int hc = 0; hc < 8; ++hc) {
                if (hc + 3 < 8) {
#pragma unroll
                    for (int i = 0; i < 8; ++i)
                        vs[hc % 3][i] = ldg_coh16(csrc[hc + 3] + i * 4096 + tid * 16);
                }
                const char* bc = ((hc + 1) & 1) ? buf1 : buf0;
#pragma unroll
                for (int i = 0; i < 4; ++i)
                    af[0][i] = *(const half8*)(bc + laneoff + (mi * 4 + i) * 256);
#pragma unroll
                for (int kl = 0; kl < 4; ++kl) {
                    const int kidx = 2 + hc * 4 + kl;
                    if (kl < 3) {
#pragma unroll
                        for (int i = 0; i < 4; ++i)
                            af[(kl + 1) & 1][i] = *(const half8*)(bc + (kl + 1) * 8192 + laneoff + (mi * 4 + i) * 256);
                    }
#pragma unroll
                    for (int i = 0; i < 4; ++i)
#pragma unroll
                        for (int g = 0; g < 4; ++g)
                            acc[i][g] = __builtin_amdgcn_mfma_f32_16x16x32_f16(
                                af[kl & 1][i], wfr[kidx & 1][g], acc[i][g], 0, 0, 0);
                    if (kidx + 2 < 34) {
#pragma unroll
                        for (int g = 0; g < 4; ++g)
                            wfr[kidx & 1][g] = *(const half8*)(WAb + (size_t)wktA(a, kidx + 2) * 4096 + g * 1024 + lane * 16);
                    }
                }
                if (hc + 1 < 8) {
                    char* bw = (hc & 1) ? buf1 : buf0;
#pragma unroll
                    for (int i = 0; i < 8; ++i)
                        *(half8*)(bw + i * 4096 + tid * 16) = vs[(hc + 1) % 3][i];
                }
                __syncthreads();
            }
#pragma unroll
            for (int i = 0; i < 4; ++i)
#pragma unroll
                for (int r = 0; r < 4; ++r) {
                    float iv = acc[i][0][r] + bias[0];
                    float fv = acc[i][1][r] + bias[1];
                    float gv = acc[i][2][r] + bias[2];
                    float ov = acc[i][3][r] + bias[3];
                    float cn = sigf(fv) * cst[i][r] + sigf(iv) * tanhf(gv);
                    float h  = sigf(ov) * tanhf(cn);
                    cst[i][r] = cn;
                    int brow = (mi * 4 + i) * 16 + quad * 4 + r;
                    stg_coh_h(h1w + a * 8192 + stoff + brow * 16, h);
                }
            publish(fA + a * FSTRIDE, t + 1);
        }
    } else {
        // ================= output: 2 blocks x 64 batch, K=1024, reg weights ===========
        const int cb = blk - NBB - NAB;
        half8 wfrC[4][8];
#pragma unroll
        for (int nt = 0; nt < 4; ++nt) {
            int row = nt * 16 + cl;
#pragma unroll
            for (int kk = 0; kk < 8; ++kk)
                wfrC[nt][kk] = cvt8(Wout + (size_t)row * 1024 + (w * 8 + kk) * 32 + quad * 8);
        }
        float bo4[4];
#pragma unroll
        for (int nt = 0; nt < 4; ++nt) bo4[nt] = bout[nt * 16 + cl];
        float* red = (float*)smem;

        for (int t = 0; t < TSTEPS; ++t) {
            if (tid < 64) {
                while (!__all(ld_flag(fB, lane & 31) >= t + 1))
                    __builtin_amdgcn_s_sleep(1);
            }
            __syncthreads();
            const char* h2c = H2 + (size_t)(t & 1) * PH;
            float4_ acc[4][4];
#pragma unroll
            for (int m = 0; m < 4; ++m)
#pragma unroll
                for (int nt = 0; nt < 4; ++nt) acc[m][nt] = (float4_){0.f, 0.f, 0.f, 0.f};
#pragma unroll
            for (int kk = 0; kk < 8; ++kk) {
                half8 afc[4];
#pragma unroll
                for (int m = 0; m < 4; ++m)
                    afc[m] = ldg_coh16(h2c + (size_t)(w * 8 + kk) * 8192 + quad * 2048 + (cb * 64 + m * 16 + cl) * 16);
#pragma unroll
                for (int m = 0; m < 4; ++m)
#pragma unroll
                    for (int nt = 0; nt < 4; ++nt)
                        acc[m][nt] = __builtin_amdgcn_mfma_f32_16x16x32_f16(afc[m], wfrC[nt][kk], acc[m][nt], 0, 0, 0);
            }
#pragma unroll
            for (int r = 0; r < 4; ++r) {
                if (w != r) {
#pragma unroll
                    for (int nt = 0; nt < 4; ++nt)
                        *(float4_*)&red[((w * 4 + nt) * 64 + lane) * 4] = acc[r][nt];
                }
                __syncthreads();
                if (w == r) {
#pragma unroll
                    for (int wo = 0; wo < 4; ++wo) if (wo != r)
#pragma unroll
                        for (int nt = 0; nt < 4; ++nt)
                            acc[r][nt] += *(const float4_*)&red[((wo * 4 + nt) * 64 + lane) * 4];
                }
                __syncthreads();
            }
            float4_ mine[4];
#pragma unroll
            for (int r = 0; r < 4; ++r) if (w == r) {
#pragma unroll
                for (int nt = 0; nt < 4; ++nt) mine[nt] = acc[r][nt];
            }
#pragma unroll
            for (int nt = 0; nt < 4; ++nt)
#pragma unroll
                for (int r = 0; r < 4; ++r) {
                    int bq = cb * 64 + w * 16 + quad * 4 + r;
                    out[(size_t)bq * 32768 + (size_t)t * 64 + nt * 16 + cl] = mine[nt][r] + bo4[nt];
                }
            publish(fC + cb * FSTRIDE, t + 1);
        }
    }
}

extern "C" void kernel_launch(void* const* d_in, const int* in_sizes, int n_in,
                              void* d_out, int out_size, void* d_ws, size_t ws_size,
                              hipStream_t stream) {
    const float* inp  = (const float*)d_in[0];
    const float* Wih1 = (const float*)d_in[1];
    const float* Whh1 = (const float*)d_in[2];
    const float* bih1 = (const float*)d_in[3];
    const float* bhh1 = (const float*)d_in[4];
    const float* Wih2 = (const float*)d_in[5];
    const float* Whh2 = (const float*)d_in[6];
    const float* bih2 = (const float*)d_in[7];
    const float* bhh2 = (const float*)d_in[8];
    const float* Wout = (const float*)d_in[9];
    const float* bout = (const float*)d_in[10];
    char* ws = (char*)d_ws;

    hipMemsetAsync(d_ws, 0, ZERO_BYTES, stream);               // flags + H1 + H2
    prep_w<<<6272, 256, 0, stream>>>(Wih1, Whh1, Wih2, Whh2, ws);
    lstm_persistent<<<NBLK, 256, 0, stream>>>(inp, bih1, bhh1, bih2, bhh2,
                                              Wout, bout, ws, (float*)d_out);
}

// Round 7
// 6516.270 us; speedup vs baseline: 3.3289x; 3.3289x over previous
//
#include <hip/hip_runtime.h>
#include <hip/hip_fp16.h>

typedef _Float16 half8 __attribute__((ext_vector_type(8)));
typedef _Float16 half4_t __attribute__((ext_vector_type(4)));
typedef float    float4_ __attribute__((ext_vector_type(4)));

#define TSTEPS 512
#define NA 64
#define NB 128
#define NC 8
#define FSTRIDE 32                // ints per flag slot = 128 B (own cache line)

// workspace layout (bytes)
#define FLA_OFF   0               // 64 flags  x 128 B
#define FLB_OFF   8192            // 128 flags x 128 B
#define FLC_OFF   24576           // 8 flags   x 128 B
#define H1_OFF    32768
#define H1_PHASE  262144          // 1024 cols x 128 batch x 2B, fragment-major
#define H2_OFF    (H1_OFF + 2 * H1_PHASE)
#define X_OFF     (H2_OFF + 2 * H1_PHASE)
#define X_TSTRIDE 16384           // 64 cols x 128 batch x 2B per step
#define ZERO_BYTES X_OFF          // flags + H1 + H2 zeroed each call

__device__ __forceinline__ float sigf(float x) { return 1.0f / (1.0f + __expf(-x)); }

__device__ __forceinline__ half8 zero8() {
    half8 z;
#pragma unroll
    for (int j = 0; j < 8; ++j) z[j] = (_Float16)0.0f;
    return z;
}

__device__ __forceinline__ half8 wfrag_load(const float* Wa, int lda,
                                            const float* Wb, int ldb,
                                            int split, int row, int k0) {
    const float* s = (k0 < split) ? (Wa + (size_t)row * lda + k0)
                                  : (Wb + (size_t)row * ldb + (k0 - split));
    float4_ lo = *(const float4_*)s;
    float4_ hi = *(const float4_*)(s + 4);
    half8 r;
    r[0] = (_Float16)lo[0]; r[1] = (_Float16)lo[1];
    r[2] = (_Float16)lo[2]; r[3] = (_Float16)lo[3];
    r[4] = (_Float16)hi[0]; r[5] = (_Float16)hi[1];
    r[6] = (_Float16)hi[2]; r[7] = (_Float16)hi[3];
    return r;
}

// ---- coherence-point access primitives (NO fences, NO buffer_inv/wbl2) ----

// 16B device-scope-coherent plain load (sc1: reads the coherence point, never
// hits a stale per-XCD L2 line; coalesces like a normal load — one 128B line
// request per 8 contiguous lanes instead of 64 separate 8B atomic requests).
// NOTE: compiler does NOT insert s_waitcnt for asm loads — consumer must pass
// the value through a VMWAIT* fence below before use.
__device__ __forceinline__ half8 ldg_sc1_16(const void* p) {
    half8 r;
    asm volatile("global_load_dwordx4 %0, %1, off sc1" : "=v"(r) : "v"(p));
    return r;
}

// drain all outstanding vmem; ties the listed fragments so no consumer of them
// can be scheduled before the wait.
#define VMWAIT8(A) asm volatile("s_waitcnt vmcnt(0)" : \
    "+v"((A)[0]), "+v"((A)[1]), "+v"((A)[2]), "+v"((A)[3]), \
    "+v"((A)[4]), "+v"((A)[5]), "+v"((A)[6]), "+v"((A)[7]) :: "memory")
#define VMWAIT9(A) asm volatile("s_waitcnt vmcnt(0)" : \
    "+v"((A)[0]), "+v"((A)[1]), "+v"((A)[2]), "+v"((A)[3]), "+v"((A)[4]), \
    "+v"((A)[5]), "+v"((A)[6]), "+v"((A)[7]), "+v"((A)[8]) :: "memory")
#define VMWAIT16(A) asm volatile("s_waitcnt vmcnt(0)" : \
    "+v"((A)[0]), "+v"((A)[1]), "+v"((A)[2]), "+v"((A)[3]), "+v"((A)[4]), \
    "+v"((A)[5]), "+v"((A)[6]), "+v"((A)[7]), "+v"((A)[8]), "+v"((A)[9]), \
    "+v"((A)[10]), "+v"((A)[11]), "+v"((A)[12]), "+v"((A)[13]), \
    "+v"((A)[14]), "+v"((A)[15]) :: "memory")

// 2B write-through store (sc0 sc1): lands at the coherence point, acked by vmcnt.
__device__ __forceinline__ void stg_coh_h(void* p, float v) {
    union { _Float16 h; unsigned short s; } u;
    u.h = (_Float16)v;
    unsigned int d = u.s;
    asm volatile("global_store_short %0, %1, off sc0 sc1" :: "v"(p), "v"(d) : "memory");
}

__device__ __forceinline__ void stg_coh_int(void* p, int v) {
    asm volatile("global_store_dword %0, %1, off sc0 sc1" :: "v"(p), "v"(v) : "memory");
}

// producer-side ordering: my write-through stores acked (vmcnt 0), then block
// barrier, then (thread 0) flag store. No cache maintenance involved.
__device__ __forceinline__ void publish(int* fbase, int idx, int v) {
    asm volatile("s_waitcnt vmcnt(0)" ::: "memory");
    __syncthreads();
    if (threadIdx.x == 0) stg_coh_int(fbase + idx * FSTRIDE, v);
}

// ---- de-contended flag waits: flags on private lines, ONE polling wave ----

__device__ __forceinline__ int ld_flag(const int* f, int idx) {
    return __hip_atomic_load(f + idx * FSTRIDE, __ATOMIC_RELAXED,
                             __HIP_MEMORY_SCOPE_AGENT);
}

// A-group: need all fA >= t (h1[t-1] ready) and all fB >= t-1 (phase free)
__device__ __forceinline__ void waitA(const int* fA, const int* fB, int t) {
    if (threadIdx.x < 64) {
        const int lane = threadIdx.x;
        for (;;) {
            int a  = ld_flag(fA, lane);
            int b0 = ld_flag(fB, lane);
            int b1 = ld_flag(fB, 64 + lane);
            if (__all((a >= t) && (b0 >= t - 1) && (b1 >= t - 1))) break;
            __builtin_amdgcn_s_sleep(1);
        }
    }
    __syncthreads();
}

// B-group: fA >= t+1 (h1[t]), fB >= t (h2[t-1]), fC >= t-1 (phase free)
__device__ __forceinline__ void waitB(const int* fA, const int* fB, const int* fC, int t) {
    if (threadIdx.x < 64) {
        const int lane = threadIdx.x;
        for (;;) {
            int a  = ld_flag(fA, lane);
            int b0 = ld_flag(fB, lane);
            int b1 = ld_flag(fB, 64 + lane);
            int c  = ld_flag(fC, lane & 7);
            if (__all((a >= t + 1) && (b0 >= t) && (b1 >= t) && (c >= t - 1))) break;
            __builtin_amdgcn_s_sleep(1);
        }
    }
    __syncthreads();
}

// C-group: fB >= t+1 (h2[t] ready)
__device__ __forceinline__ void waitC(const int* fB, int t) {
    if (threadIdx.x < 64) {
        const int lane = threadIdx.x;
        for (;;) {
            int b0 = ld_flag(fB, lane);
            int b1 = ld_flag(fB, 64 + lane);
            if (__all((b0 >= t + 1) && (b1 >= t + 1))) break;
            __builtin_amdgcn_s_sleep(1);
        }
    }
    __syncthreads();
}

// Convert input [128 b][512 t][64 i] fp32 -> fragment-major fp16 X[t][kt][quad][b][j]
extern "C" __global__ void prep_x(const float* __restrict__ in, char* __restrict__ ws) {
    const int t = blockIdx.x;
    char* X = ws + X_OFF + (size_t)t * X_TSTRIDE;
    for (int idx = threadIdx.x; idx < 8192; idx += 256) {
        int kt = idx >> 12, rem = idx & 4095;
        int quad = rem >> 10, rem2 = rem & 1023;
        int b = rem2 >> 3, j = rem2 & 7;
        int i = kt * 32 + quad * 8 + j;
        float v = in[(size_t)b * 32768 + (size_t)t * 64 + i];
        *(_Float16*)(X + (size_t)idx * 2) = (_Float16)v;
    }
}

extern "C" __global__ __launch_bounds__(256, 1)
void lstm_persistent(const float* __restrict__ Wih1, const float* __restrict__ Whh1,
                     const float* __restrict__ bih1, const float* __restrict__ bhh1,
                     const float* __restrict__ Wih2, const float* __restrict__ Whh2,
                     const float* __restrict__ bih2, const float* __restrict__ bhh2,
                     const float* __restrict__ Wout, const float* __restrict__ bout,
                     char* __restrict__ ws, float* __restrict__ out) {
    const int tid = threadIdx.x;
    const int w = tid >> 6, lane = tid & 63;
    const int quad = lane >> 4, cl = lane & 15;
    const int laneoff = quad * 2048 + cl * 16;
    int* fA = (int*)(ws + FLA_OFF);
    int* fB = (int*)(ws + FLB_OFF);
    int* fC = (int*)(ws + FLC_OFF);
    char* H1 = ws + H1_OFF;
    char* H2 = ws + H2_OFF;
    char* X  = ws + X_OFF;
    const int blk = blockIdx.x;
    __shared__ float redbuf[8192];

    if (blk < NA) {
        // ---------- layer-1: h1 cols [c0,c0+16), K = 1088 (34 k-tiles), waves split K
        const int c0 = blk * 16;
        const int kbase = w * 9;
        half8 wfr[4][9];
#pragma unroll
        for (int nt = 0; nt < 4; ++nt) {
            int row = nt * 1024 + c0 + cl;
#pragma unroll
            for (int kk = 0; kk < 9; ++kk) {
                int ktg = kbase + kk;
                if (ktg < 34) wfr[nt][kk] = wfrag_load(Wih1, 64, Whh1, 1024, 64, row, ktg * 32 + quad * 8);
                else          wfr[nt][kk] = zero8();
            }
        }
        float ba[4];
#pragma unroll
        for (int g = 0; g < 4; ++g) ba[g] = bih1[g * 1024 + c0 + cl] + bhh1[g * 1024 + c0 + cl];
        float cst[2][4];
#pragma unroll
        for (int mi = 0; mi < 2; ++mi)
#pragma unroll
            for (int r = 0; r < 4; ++r) cst[mi][r] = 0.0f;
        const int cc = c0 + cl;
        const int woffbase = (cc >> 5) * 8192 + ((cc >> 3) & 3) * 2048 + (cc & 7) * 2;

        for (int t = 0; t < TSTEPS; ++t) {
            waitA(fA, fB, t);

            const char* xb  = X + (size_t)t * X_TSTRIDE;
            const char* h1r = H1 + (((t & 1) ^ 1) ? H1_PHASE : 0);
            char*       h1w = H1 + ((t & 1) ? H1_PHASE : 0);
            const char* kb[9];
#pragma unroll
            for (int kk = 0; kk < 9; ++kk) {
                int ktg = kbase + kk; if (ktg > 33) ktg = 33;
                kb[kk] = (ktg < 2) ? (xb + ktg * 8192) : (h1r + (ktg - 2) * 8192);
            }
            float4_ acc[8][4];
#pragma unroll
            for (int mt = 0; mt < 8; ++mt)
#pragma unroll
                for (int nt = 0; nt < 4; ++nt) acc[mt][nt] = (float4_){0.f, 0.f, 0.f, 0.f};
            half8 af[2][9];
#pragma unroll
            for (int kk = 0; kk < 9; ++kk) af[0][kk] = ldg_sc1_16(kb[kk] + laneoff);
#pragma unroll
            for (int mt = 0; mt < 8; ++mt) {
                const int cur = mt & 1;
                VMWAIT9(af[cur]);
                if (mt < 7) {
#pragma unroll
                    for (int kk = 0; kk < 9; ++kk)
                        af[cur ^ 1][kk] = ldg_sc1_16(kb[kk] + laneoff + (mt + 1) * 256);
                }
#pragma unroll
                for (int kk = 0; kk < 9; ++kk)
#pragma unroll
                    for (int nt = 0; nt < 4; ++nt)
                        acc[mt][nt] = __builtin_amdgcn_mfma_f32_16x16x32_f16(
                            af[cur][kk], wfr[nt][kk], acc[mt][nt], 0, 0, 0);
            }
#pragma unroll
            for (int r = 0; r < 4; ++r) {
                if (w != r) {
#pragma unroll
                    for (int mi = 0; mi < 2; ++mi)
#pragma unroll
                        for (int nt = 0; nt < 4; ++nt)
                            *(float4_*)&redbuf[(((w * 2 + mi) * 4 + nt) * 64 + lane) * 4] = acc[2 * r + mi][nt];
                }
                __syncthreads();
                if (w == r) {
#pragma unroll
                    for (int wo = 0; wo < 4; ++wo) if (wo != r) {
#pragma unroll
                        for (int mi = 0; mi < 2; ++mi)
#pragma unroll
                            for (int nt = 0; nt < 4; ++nt)
                                acc[2 * r + mi][nt] += *(const float4_*)&redbuf[(((wo * 2 + mi) * 4 + nt) * 64 + lane) * 4];
                    }
                }
                __syncthreads();
            }
            float4_ mine[2][4];
#pragma unroll
            for (int r = 0; r < 4; ++r) if (w == r) {
#pragma unroll
                for (int mi = 0; mi < 2; ++mi)
#pragma unroll
                    for (int nt = 0; nt < 4; ++nt) mine[mi][nt] = acc[2 * r + mi][nt];
            }
#pragma unroll
            for (int mi = 0; mi < 2; ++mi) {
#pragma unroll
                for (int r = 0; r < 4; ++r) {
                    float iv = mine[mi][0][r] + ba[0];
                    float fv = mine[mi][1][r] + ba[1];
                    float gv = mine[mi][2][r] + ba[2];
                    float ov = mine[mi][3][r] + ba[3];
                    float c = sigf(fv) * cst[mi][r] + sigf(iv) * tanhf(gv);
                    float h = sigf(ov) * tanhf(c);
                    cst[mi][r] = c;
                    int m = (2 * w + mi) * 16 + quad * 4 + r;
                    stg_coh_h(h1w + woffbase + m * 16, h);
                }
            }
            publish(fA, blk, t + 1);
        }
    } else if (blk < NA + NB) {
        // ---------- layer-2: h2 cols [c0,c0+8), K = 2048 (64 k-tiles), waves split K
        const int bb = blk - NA;
        const int c0 = bb * 8;
        const int kbase = w * 16;
        const int colB = c0 + (cl & 7);
        const int row0 = (cl < 8) ? colB : (1024 + colB);
        const int row1 = (cl < 8) ? (2048 + colB) : (3072 + colB);
        half8 wfr[2][16];
#pragma unroll
        for (int kk = 0; kk < 16; ++kk) {
            int k0 = (kbase + kk) * 32 + quad * 8;
            wfr[0][kk] = wfrag_load(Wih2, 1024, Whh2, 1024, 1024, row0, k0);
            wfr[1][kk] = wfrag_load(Wih2, 1024, Whh2, 1024, 1024, row1, k0);
        }
        const float bi = bih2[colB] + bhh2[colB];
        const float bf = bih2[1024 + colB] + bhh2[1024 + colB];
        const float bg = bih2[2048 + colB] + bhh2[2048 + colB];
        const float bo = bih2[3072 + colB] + bhh2[3072 + colB];
        float cst[2][4];
#pragma unroll
        for (int mi = 0; mi < 2; ++mi)
#pragma unroll
            for (int r = 0; r < 4; ++r) cst[mi][r] = 0.0f;
        const int woffbase = (c0 >> 5) * 8192 + ((c0 >> 3) & 3) * 2048 + (cl & 7) * 2;
        const bool lolane = (cl & 8) == 0;

        for (int t = 0; t < TSTEPS; ++t) {
            waitB(fA, fB, fC, t);

            const char* h1c = H1 + ((t & 1) ? H1_PHASE : 0);
            const char* h2r = H2 + (((t & 1) ^ 1) ? H1_PHASE : 0);
            char*       h2w = H2 + ((t & 1) ? H1_PHASE : 0);
            const char* kb[16];
#pragma unroll
            for (int kk = 0; kk < 16; ++kk) {
                int ktg = kbase + kk;
                kb[kk] = (ktg < 32) ? (h1c + ktg * 8192) : (h2r + (ktg - 32) * 8192);
            }
            float4_ acc[8][2];
#pragma unroll
            for (int mt = 0; mt < 8; ++mt) {
                acc[mt][0] = (float4_){0.f, 0.f, 0.f, 0.f};
                acc[mt][1] = (float4_){0.f, 0.f, 0.f, 0.f};
            }
            half8 af[2][16];
#pragma unroll
            for (int kk = 0; kk < 16; ++kk) af[0][kk] = ldg_sc1_16(kb[kk] + laneoff);
#pragma unroll
            for (int mt = 0; mt < 8; ++mt) {
                const int cur = mt & 1;
                VMWAIT16(af[cur]);
                if (mt < 7) {
#pragma unroll
                    for (int kk = 0; kk < 16; ++kk)
                        af[cur ^ 1][kk] = ldg_sc1_16(kb[kk] + laneoff + (mt + 1) * 256);
                }
#pragma unroll
                for (int kk = 0; kk < 16; ++kk) {
                    acc[mt][0] = __builtin_amdgcn_mfma_f32_16x16x32_f16(af[cur][kk], wfr[0][kk], acc[mt][0], 0, 0, 0);
                    acc[mt][1] = __builtin_amdgcn_mfma_f32_16x16x32_f16(af[cur][kk], wfr[1][kk], acc[mt][1], 0, 0, 0);
                }
            }
#pragma unroll
            for (int r = 0; r < 4; ++r) {
                if (w != r) {
#pragma unroll
                    for (int mi = 0; mi < 2; ++mi)
#pragma unroll
                        for (int nt = 0; nt < 2; ++nt)
                            *(float4_*)&redbuf[(((w * 2 + mi) * 2 + nt) * 64 + lane) * 4] = acc[2 * r + mi][nt];
                }
                __syncthreads();
                if (w == r) {
#pragma unroll
                    for (int wo = 0; wo < 4; ++wo) if (wo != r) {
#pragma unroll
                        for (int mi = 0; mi < 2; ++mi)
#pragma unroll
                            for (int nt = 0; nt < 2; ++nt)
                                acc[2 * r + mi][nt] += *(const float4_*)&redbuf[(((wo * 2 + mi) * 2 + nt) * 64 + lane) * 4];
                    }
                }
                __syncthreads();
            }
            float4_ mine[2][2];
#pragma unroll
            for (int r = 0; r < 4; ++r) if (w == r) {
#pragma unroll
                for (int mi = 0; mi < 2; ++mi) {
                    mine[mi][0] = acc[2 * r + mi][0];
                    mine[mi][1] = acc[2 * r + mi][1];
                }
            }
#pragma unroll
            for (int mi = 0; mi < 2; ++mi) {
#pragma unroll
                for (int r = 0; r < 4; ++r) {
                    float d0 = mine[mi][0][r], d1 = mine[mi][1][r];
                    float s0 = __shfl_xor(d0, 8, 64);
                    float s1 = __shfl_xor(d1, 8, 64);
                    float iv = (lolane ? d0 : s0) + bi;
                    float fv = (lolane ? s0 : d0) + bf;
                    float gv = (lolane ? d1 : s1) + bg;
                    float ov = (lolane ? s1 : d1) + bo;
                    float c = sigf(fv) * cst[mi][r] + sigf(iv) * tanhf(gv);
                    float h = sigf(ov) * tanhf(c);
                    cst[mi][r] = c;
                    if (lolane) {
                        int m = (2 * w + mi) * 16 + quad * 4 + r;
                        stg_coh_h(h2w + woffbase + m * 16, h);
                    }
                }
            }
            publish(fB, bb, t + 1);
        }
    } else {
        // ---------- output: batch tile cb, y = h2 @ Wout^T + bout, K = 1024
        const int cb = blk - NA - NB;
        const int kbase = w * 8;
        half8 wfr[4][8];
#pragma unroll
        for (int nt = 0; nt < 4; ++nt) {
            int row = nt * 16 + cl;
#pragma unroll
            for (int kk = 0; kk < 8; ++kk)
                wfr[nt][kk] = wfrag_load(Wout, 1024, Wout, 1024, 1 << 30, row, (kbase + kk) * 32 + quad * 8);
        }
        const float bo_ = bout[w * 16 + cl];

        for (int t = 0; t < TSTEPS; ++t) {
            waitC(fB, t);
            const char* h2c = H2 + ((t & 1) ? H1_PHASE : 0);
            float4_ acc[4];
#pragma unroll
            for (int nt = 0; nt < 4; ++nt) acc[nt] = (float4_){0.f, 0.f, 0.f, 0.f};
            half8 af[8];
#pragma unroll
            for (int kk = 0; kk < 8; ++kk)
                af[kk] = ldg_sc1_16(h2c + (kbase + kk) * 8192 + laneoff + cb * 256);
            VMWAIT8(af);
#pragma unroll
            for (int kk = 0; kk < 8; ++kk)
#pragma unroll
                for (int nt = 0; nt < 4; ++nt)
                    acc[nt] = __builtin_amdgcn_mfma_f32_16x16x32_f16(af[kk], wfr[nt][kk], acc[nt], 0, 0, 0);
#pragma unroll
            for (int r = 0; r < 4; ++r) {
                if (w != r) *(float4_*)&redbuf[(w * 64 + lane) * 4] = acc[r];
                __syncthreads();
                if (w == r) {
#pragma unroll
                    for (int wo = 0; wo < 4; ++wo) if (wo != r)
                        acc[r] += *(const float4_*)&redbuf[(wo * 64 + lane) * 4];
                }
                __syncthreads();
            }
            float4_ myy = acc[0];
#pragma unroll
            for (int r = 1; r < 4; ++r) if (w == r) myy = acc[r];
#pragma unroll
            for (int r = 0; r < 4; ++r) {
                int m = cb * 16 + quad * 4 + r;
                out[(size_t)m * 32768 + (size_t)t * 64 + (w * 16 + cl)] = myy[r] + bo_;
            }
            publish(fC, cb, t + 1);
        }
    }
}

extern "C" void kernel_launch(void* const* d_in, const int* in_sizes, int n_in,
                              void* d_out, int out_size, void* d_ws, size_t ws_size,
                              hipStream_t stream) {
    const float* inp  = (const float*)d_in[0];
    const float* Wih1 = (const float*)d_in[1];
    const float* Whh1 = (const float*)d_in[2];
    const float* bih1 = (const float*)d_in[3];
    const float* bhh1 = (const float*)d_in[4];
    const float* Wih2 = (const float*)d_in[5];
    const float* Whh2 = (const float*)d_in[6];
    const float* bih2 = (const float*)d_in[7];
    const float* bhh2 = (const float*)d_in[8];
    const float* Wout = (const float*)d_in[9];
    const float* bout = (const float*)d_in[10];
    char* ws = (char*)d_ws;

    hipMemsetAsync(d_ws, 0, ZERO_BYTES, stream);
    prep_x<<<TSTEPS, 256, 0, stream>>>(inp, ws);
    lstm_persistent<<<NA + NB + NC, 256, 0, stream>>>(Wih1, Whh1, bih1, bhh1,
                                                      Wih2, Whh2, bih2, bhh2,
                                                      Wout, bout, ws, (float*)d_out);
}